// Round 3
// baseline (120.479 us; speedup 1.0000x reference)
//
#include <hip/hip_runtime.h>
#include <hip/hip_bf16.h>

// Non-backtracking random walk, one thread per walk, 32 sequential steps.
// out = [walks (steps+1,n) ; walk_edges (steps,n)] as int32.
//
// R3: latency-bound on the per-step adj_nodes gather (R2 counters: VALUBusy
// 3.5%, ~600cyc mixed L2/L3 latency at per-CU MLP cap). Fixes:
//  (a) repack adjacency 6.4MB int32 -> 3.2MB uint16 lo + 200KB hi-bit array
//      in d_ws (fits per-XCD 4MiB L2 -> L2-hit latency ~200cyc). The three
//      loads per step (lo[chosen], lo[alt], hi[cur]) are mutually independent.
//  (b) nontemporal streaming loads/stores for choices + outputs so they
//      don't evict the L2-resident adjacency.
// Pack kernel also verifies CSR uniformity (deg==16, offset==16v) and
// node-id range (<2^17); on violation the walker takes a general fallback.

#define DEG 16

__global__ void pack_check_kernel(const int* __restrict__ adj_nodes,
                                  const int* __restrict__ adj_offset,
                                  const int* __restrict__ degrees,
                                  int n,
                                  unsigned short* __restrict__ lo,
                                  unsigned short* __restrict__ hi,
                                  int* __restrict__ flag) {
    int v = blockIdx.x * blockDim.x + threadIdx.x;
    if (v >= n) return;

    bool bad = (degrees[v] != DEG) || (adj_offset[v] != v * DEG);

    const int* row = adj_nodes + (size_t)v * DEG;
    union { unsigned short u16[DEG]; uint4 v4[2]; } p;
    unsigned hbits = 0;
#pragma unroll
    for (int j = 0; j < DEG; ++j) {
        unsigned u = (unsigned)row[j];
        if (u >= 131072u) bad = true;          // needs >17 bits -> no pack
        p.u16[j] = (unsigned short)(u & 0xffffu);
        hbits |= ((u >> 16) & 1u) << j;
    }
    uint4* dst = (uint4*)(lo + (size_t)v * DEG);   // 32B-aligned (base 16B-aligned + v*32B)
    dst[0] = p.v4[0];
    dst[1] = p.v4[1];
    hi[v] = (unsigned short)hbits;

    if (bad) atomicOr(flag, 1);
}

template <int STEPS>
__global__ __launch_bounds__(128) void walker_fast(
    const int* __restrict__ adj_nodes,
    const int* __restrict__ adj_offset,
    const int* __restrict__ degrees,
    const int* __restrict__ choices,
    const unsigned short* __restrict__ lo,
    const unsigned short* __restrict__ hi,
    int* __restrict__ out, int n,
    const int* __restrict__ flag) {

    int w = blockIdx.x * blockDim.x + threadIdx.x;
    if (w >= n) return;

    int* walks      = out;                    // [STEPS+1, n]
    int* walk_edges = out + (STEPS + 1) * n;  // [STEPS, n]
    __builtin_nontemporal_store(w, &walks[w]);

    if (*flag == 0) {
        // ---- fast path: uniform CSR, deg=16, packed L2-resident adjacency ----
        int chs[STEPS];
#pragma unroll
        for (int i = 0; i < STEPS; ++i)
            chs[i] = __builtin_nontemporal_load(&choices[i * n + w]);

        int prev = -1, cur = w;
#pragma unroll
        for (int i = 0; i < STEPS; ++i) {
            int ch  = chs[i];
            int e   = ch & (DEG - 1);
            int ae  = (e + 1 + ch % (DEG - 1)) & (DEG - 1);
            int base = cur << 4;                       // cur * DEG

            // three independent loads, all L2-resident (3.4MB working set)
            unsigned l0 = lo[base + e];
            unsigned l1 = lo[base + ae];
            unsigned hb = hi[cur];

            int nw0 = (int)(l0 | (((hb >> e)  & 1u) << 16));
            int nw1 = (int)(l1 | (((hb >> ae) & 1u) << 16));

            bool bt = (nw0 == prev);
            int nw  = bt ? nw1 : nw0;
            __builtin_nontemporal_store(nw, &walks[(i + 1) * n + w]);
            __builtin_nontemporal_store(base + (bt ? ae : e), &walk_edges[i * n + w]);
            prev = cur;
            cur  = nw;
        }
    } else {
        // ---- general fallback (2 dependent gathers per step) ----
        int prev = -1, cur = w;
        for (int i = 0; i < STEPS; ++i) {
            int ch  = choices[i * n + w];
            int deg = degrees[cur];
            int off = adj_offset[cur];
            int nb  = deg - 1 > 1 ? deg - 1 : 1;

            int e      = ch % deg;
            int chosen = off + e;
            int alt    = off + (e + 1 + ch % nb) % deg;

            int nw0 = adj_nodes[chosen];
            int nw1 = adj_nodes[alt];

            bool bt = (nw0 == prev);
            int nw  = bt ? nw1 : nw0;
            walks[(i + 1) * n + w] = nw;
            walk_edges[i * n + w]  = bt ? alt : chosen;
            prev = cur;
            cur  = nw;
        }
    }
}

__global__ __launch_bounds__(256) void walker_generic(
    const int* __restrict__ adj_nodes,
    const int* __restrict__ adj_offset,
    const int* __restrict__ degrees,
    const int* __restrict__ choices,
    int* __restrict__ out, int n, int steps) {

    int w = blockIdx.x * blockDim.x + threadIdx.x;
    if (w >= n) return;

    int* walks      = out;
    int* walk_edges = out + (steps + 1) * n;
    walks[w] = w;

    int prev = -1, cur = w;
    for (int i = 0; i < steps; ++i) {
        int ch  = choices[i * n + w];
        int deg = degrees[cur];
        int off = adj_offset[cur];
        int nb  = deg - 1 > 1 ? deg - 1 : 1;

        int e      = ch % deg;
        int chosen = off + e;
        int alt    = off + (e + 1 + ch % nb) % deg;

        int nw0 = adj_nodes[chosen];
        int nw1 = adj_nodes[alt];

        bool bt = (nw0 == prev);
        int nw  = bt ? nw1 : nw0;
        walks[(i + 1) * n + w] = nw;
        walk_edges[i * n + w]  = bt ? alt : chosen;
        prev = cur;
        cur  = nw;
    }
}

extern "C" void kernel_launch(void* const* d_in, const int* in_sizes, int n_in,
                              void* d_out, int out_size, void* d_ws, size_t ws_size,
                              hipStream_t stream) {
    // inputs: 0=x (unused), 1=adj_nodes, 2=adj_offset, 3=degrees, 4=choices
    const int* adj_nodes  = (const int*)d_in[1];
    const int* adj_offset = (const int*)d_in[2];
    const int* degrees    = (const int*)d_in[3];
    const int* choices    = (const int*)d_in[4];
    int* out = (int*)d_out;

    int n     = in_sizes[2];
    int steps = in_sizes[4] / n;

    // ws layout: [0,4) flag | [64, 64+2n*DEG) lo (uint16) | then hi (uint16/node)
    size_t lo_off = 64;
    size_t lo_bytes = (size_t)n * DEG * sizeof(unsigned short);
    size_t hi_off = lo_off + ((lo_bytes + 63) & ~(size_t)63);
    size_t need = hi_off + (size_t)n * sizeof(unsigned short);

    if (steps == 32 && ws_size >= need) {
        int* flag = (int*)d_ws;
        unsigned short* lo = (unsigned short*)((char*)d_ws + lo_off);
        unsigned short* hi = (unsigned short*)((char*)d_ws + hi_off);

        hipMemsetAsync(flag, 0, sizeof(int), stream);
        int pb = 256, pg = (n + pb - 1) / pb;
        pack_check_kernel<<<pg, pb, 0, stream>>>(adj_nodes, adj_offset, degrees,
                                                 n, lo, hi, flag);
        int wb = 128, wg = (n + wb - 1) / wb;
        walker_fast<32><<<wg, wb, 0, stream>>>(adj_nodes, adj_offset, degrees,
                                               choices, lo, hi, out, n, flag);
    } else {
        int block = 256, grid = (n + block - 1) / block;
        walker_generic<<<grid, block, 0, stream>>>(adj_nodes, adj_offset,
                                                   degrees, choices, out, n, steps);
    }
}

// Round 4
// 107.998 us; speedup vs baseline: 1.1156x; 1.1156x over previous
//
#include <hip/hip_runtime.h>
#include <hip/hip_bf16.h>

// Non-backtracking random walk, 32 steps.
// out = [walks (steps+1,n) ; walk_edges (steps,n)] int32.
//
// R4: chain is latency/MLP-bound (R2/R3: VALUBusy ~4%, more L2 residency
// didn't move total). n is fixed -> can't add waves; instead raise MLP per
// thread: each thread interleaves TWO independent walks (t and t+n/2),
// doubling outstanding gathers per wave at every chain stall.
// Adjacency packed post-poison into d_ws as stride-18 u16 rows
// (16 lo + hibits + pad = 36B, 3.6MB total -> L2/IF$-resident).

#define DEG 16

__global__ void pack_check_kernel(const int* __restrict__ adj_nodes,
                                  const int* __restrict__ adj_offset,
                                  const int* __restrict__ degrees,
                                  int n,
                                  unsigned int* __restrict__ pk32,
                                  int* __restrict__ flag) {
    int v = blockIdx.x * blockDim.x + threadIdx.x;
    if (v >= n) return;

    bool bad = (degrees[v] != DEG) || (adj_offset[v] != v * DEG);

    const int* row = adj_nodes + (size_t)v * DEG;
    unsigned w[8];
    unsigned hbits = 0;
#pragma unroll
    for (int j = 0; j < 8; ++j) {
        unsigned u0 = (unsigned)row[2 * j];
        unsigned u1 = (unsigned)row[2 * j + 1];
        if (u0 >= 131072u || u1 >= 131072u) bad = true;  // >17 bits
        w[j] = (u0 & 0xffffu) | ((u1 & 0xffffu) << 16);
        hbits |= ((u0 >> 16) & 1u) << (2 * j);
        hbits |= ((u1 >> 16) & 1u) << (2 * j + 1);
    }
    unsigned int* dst = pk32 + (size_t)v * 9;   // 36B/row, 4B-aligned
#pragma unroll
    for (int j = 0; j < 8; ++j) dst[j] = w[j];
    dst[8] = hbits;                              // u16 hbits in low half

    if (bad) atomicOr(flag, 1);
}

template <int STEPS>
__global__ __launch_bounds__(64) void walker_fast2(
    const unsigned short* __restrict__ pk,   // stride-18 u16 rows
    const int* __restrict__ choices,
    int* __restrict__ out, int n, int h,
    const int* __restrict__ flag,
    const int* __restrict__ adj_nodes,
    const int* __restrict__ adj_offset,
    const int* __restrict__ degrees) {

    int t = blockIdx.x * blockDim.x + threadIdx.x;
    if (t >= h) return;

    int* walks      = out;                    // [STEPS+1, n]
    int* walk_edges = out + (STEPS + 1) * n;  // [STEPS, n]

    int w0 = t;
    int w1 = t + h;
    bool has1 = (w1 < n);
    int w1s = has1 ? w1 : w0;                 // safe index for loads

    __builtin_nontemporal_store(w0, &walks[w0]);
    if (has1) __builtin_nontemporal_store(w1, &walks[w1]);

    if (*flag == 0) {
        // ---- fast path: uniform CSR deg=16, packed rows, 2 walks/thread ----
        int c0[STEPS], c1[STEPS];
#pragma unroll
        for (int i = 0; i < STEPS; ++i) {
            c0[i] = __builtin_nontemporal_load(&choices[i * n + w0]);
            c1[i] = __builtin_nontemporal_load(&choices[i * n + w1s]);
        }

        int prev0 = -1, cur0 = w0;
        int prev1 = -1, cur1 = w1s;
#pragma unroll
        for (int i = 0; i < STEPS; ++i) {
            int ch0 = c0[i], ch1 = c1[i];
            int e0 = ch0 & (DEG - 1);
            int e1 = ch1 & (DEG - 1);
            int a0 = (e0 + 1 + ch0 % (DEG - 1)) & (DEG - 1);
            int a1 = (e1 + 1 + ch1 % (DEG - 1)) & (DEG - 1);

            const unsigned short* r0 = pk + (unsigned)cur0 * 18u;
            const unsigned short* r1 = pk + (unsigned)cur1 * 18u;

            // six independent loads in flight per step
            unsigned l00 = r0[e0];
            unsigned l01 = r0[a0];
            unsigned hb0 = r0[16];
            unsigned l10 = r1[e1];
            unsigned l11 = r1[a1];
            unsigned hb1 = r1[16];

            int n00 = (int)(l00 | (((hb0 >> e0) & 1u) << 16));
            int n01 = (int)(l01 | (((hb0 >> a0) & 1u) << 16));
            int n10 = (int)(l10 | (((hb1 >> e1) & 1u) << 16));
            int n11 = (int)(l11 | (((hb1 >> a1) & 1u) << 16));

            bool bt0 = (n00 == prev0);
            bool bt1 = (n10 == prev1);
            int nw0 = bt0 ? n01 : n00;
            int nw1 = bt1 ? n11 : n10;
            int ce0 = (cur0 << 4) + (bt0 ? a0 : e0);
            int ce1 = (cur1 << 4) + (bt1 ? a1 : e1);

            __builtin_nontemporal_store(nw0, &walks[(i + 1) * n + w0]);
            __builtin_nontemporal_store(ce0, &walk_edges[i * n + w0]);
            if (has1) {
                __builtin_nontemporal_store(nw1, &walks[(i + 1) * n + w1]);
                __builtin_nontemporal_store(ce1, &walk_edges[i * n + w1]);
            }
            prev0 = cur0; cur0 = nw0;
            prev1 = cur1; cur1 = nw1;
        }
    } else {
        // ---- general fallback: both walks, 2 dependent gathers/step ----
        for (int k = 0; k < 2; ++k) {
            int w = (k == 0) ? w0 : w1;
            if (w >= n) break;
            int prev = -1, cur = w;
            for (int i = 0; i < STEPS; ++i) {
                int ch  = choices[i * n + w];
                int deg = degrees[cur];
                int off = adj_offset[cur];
                int nb  = deg - 1 > 1 ? deg - 1 : 1;

                int e      = ch % deg;
                int chosen = off + e;
                int alt    = off + (e + 1 + ch % nb) % deg;

                int nv0 = adj_nodes[chosen];
                int nv1 = adj_nodes[alt];

                bool bt = (nv0 == prev);
                int nw  = bt ? nv1 : nv0;
                walks[(i + 1) * n + w] = nw;
                walk_edges[i * n + w]  = bt ? alt : chosen;
                prev = cur;
                cur  = nw;
            }
        }
    }
}

__global__ __launch_bounds__(256) void walker_generic(
    const int* __restrict__ adj_nodes,
    const int* __restrict__ adj_offset,
    const int* __restrict__ degrees,
    const int* __restrict__ choices,
    int* __restrict__ out, int n, int steps) {

    int w = blockIdx.x * blockDim.x + threadIdx.x;
    if (w >= n) return;

    int* walks      = out;
    int* walk_edges = out + (steps + 1) * n;
    walks[w] = w;

    int prev = -1, cur = w;
    for (int i = 0; i < steps; ++i) {
        int ch  = choices[i * n + w];
        int deg = degrees[cur];
        int off = adj_offset[cur];
        int nb  = deg - 1 > 1 ? deg - 1 : 1;

        int e      = ch % deg;
        int chosen = off + e;
        int alt    = off + (e + 1 + ch % nb) % deg;

        int nv0 = adj_nodes[chosen];
        int nv1 = adj_nodes[alt];

        bool bt = (nv0 == prev);
        int nw  = bt ? nv1 : nv0;
        walks[(i + 1) * n + w] = nw;
        walk_edges[i * n + w]  = bt ? alt : chosen;
        prev = cur;
        cur  = nw;
    }
}

extern "C" void kernel_launch(void* const* d_in, const int* in_sizes, int n_in,
                              void* d_out, int out_size, void* d_ws, size_t ws_size,
                              hipStream_t stream) {
    // inputs: 0=x (unused), 1=adj_nodes, 2=adj_offset, 3=degrees, 4=choices
    const int* adj_nodes  = (const int*)d_in[1];
    const int* adj_offset = (const int*)d_in[2];
    const int* degrees    = (const int*)d_in[3];
    const int* choices    = (const int*)d_in[4];
    int* out = (int*)d_out;

    int n     = in_sizes[2];
    int steps = in_sizes[4] / n;

    // ws layout: [0,4) flag | [64, 64+36n) packed rows
    size_t pk_off = 64;
    size_t need   = pk_off + (size_t)n * 36;

    if (steps == 32 && ws_size >= need) {
        int* flag = (int*)d_ws;
        unsigned int* pk32  = (unsigned int*)((char*)d_ws + pk_off);
        unsigned short* pk  = (unsigned short*)pk32;

        hipMemsetAsync(flag, 0, sizeof(int), stream);
        int pb = 256, pg = (n + pb - 1) / pb;
        pack_check_kernel<<<pg, pb, 0, stream>>>(adj_nodes, adj_offset, degrees,
                                                 n, pk32, flag);
        int h  = (n + 1) / 2;
        int wb = 64, wg = (h + wb - 1) / wb;
        walker_fast2<32><<<wg, wb, 0, stream>>>(pk, choices, out, n, h, flag,
                                                adj_nodes, adj_offset, degrees);
    } else {
        int block = 256, grid = (n + block - 1) / block;
        walker_generic<<<grid, block, 0, stream>>>(adj_nodes, adj_offset,
                                                   degrees, choices, out, n, steps);
    }
}